// Round 4
// baseline (214.177 us; speedup 1.0000x reference)
//
#include <hip/hip_runtime.h>
#include <hip/hip_bf16.h>
#include <cstdint>

#define OUT_LD 3584

typedef __bf16 bf16x8 __attribute__((ext_vector_type(8)));
typedef float  f32x4  __attribute__((ext_vector_type(4)));

__device__ __forceinline__ short f2bf(float v) {
  __hip_bfloat16 h = __float2bfloat16(v);
  return *reinterpret_cast<short*>(&h);
}

__device__ __forceinline__ f32x4 mfma16(bf16x8 a, bf16x8 b, f32x4 c) {
  return __builtin_amdgcn_mfma_f32_16x16x32_bf16(a, b, c, 0, 0, 0);
}

// ---------------------------------------------------------------------------
// chain kernel: 128 blocks x 32 rows, 8 waves (512 thr), wave w owns cols
// [w*64, w*64+64). Weights streamed from L2 as register fragments (the 4
// k-groups of a wave cover full 64B cachelines). Activations held in LDS
// with ((row&7)<<4) byte-XOR swizzle (T2) so A-frag ds_reads are conflict-free.
// ---------------------------------------------------------------------------
__device__ __forceinline__ void chain_epi(
    f32x4 acc[2][4], int bm, int wc, int lane,
    float* __restrict__ zout, short* __restrict__ cbf, char* act)
{
  const int fr = lane & 15;
  const int q0 = (lane >> 4) * 4;
  #pragma unroll
  for (int i = 0; i < 2; ++i) {
    #pragma unroll
    for (int j = 0; j < 4; ++j) {
      const int col = wc + j * 16 + fr;
      #pragma unroll
      for (int q = 0; q < 4; ++q) {
        const int row = i * 16 + q0 + q;
        float rv = acc[i][j][q];
        rv = rv > 0.f ? rv : 0.f;
        zout[(size_t)(bm + row) * OUT_LD + col] = rv;
        const short bv = f2bf(rv);
        cbf[(size_t)(bm + row) * 512 + col] = bv;
        if (act) {
          const int byte = ((row * 512 + col) * 2) ^ ((row & 7) << 4);
          *(short*)(act + byte) = bv;
        }
      }
    }
  }
}

__global__ __launch_bounds__(512)
void chain_kernel(const short* __restrict__ Ybf,
                  const short* __restrict__ W1b, const short* __restrict__ W2b,
                  const short* __restrict__ W3b,
                  short* __restrict__ c1bf, short* __restrict__ c2bf,
                  short* __restrict__ c3bf, float* __restrict__ out)
{
  __shared__ __align__(16) char act[32 * 512 * 2];   // 32 KB swizzled bf16 [32][512]

  const int tid  = threadIdx.x;
  const int lane = tid & 63;
  const int wid  = tid >> 6;            // 0..7
  const int bm   = blockIdx.x * 32;
  const int wc   = wid * 64;
  const int fr   = lane & 15;
  const int fkg  = lane >> 4;           // 0..3
  const int fk   = fkg * 8;

  f32x4 acc[2][4];

  // ---- stage 1: c1 = relu(Y @ W1^T), K=1024, A from global ----
  {
    #pragma unroll
    for (int i = 0; i < 2; ++i)
      #pragma unroll
      for (int j = 0; j < 4; ++j) acc[i][j] = (f32x4){0.f, 0.f, 0.f, 0.f};
    const short* A0 = Ybf + (size_t)(bm + fr) * 1024 + fk;
    const short* B0 = W1b + (size_t)(wc + fr) * 1024 + fk;
    #pragma unroll 4
    for (int kt = 0; kt < 32; ++kt) {
      bf16x8 a0 = *(const bf16x8*)(A0 + kt * 32);
      bf16x8 a1 = *(const bf16x8*)(A0 + 16 * 1024 + kt * 32);
      bf16x8 b[4];
      #pragma unroll
      for (int j = 0; j < 4; ++j)
        b[j] = *(const bf16x8*)(B0 + (size_t)j * 16 * 1024 + kt * 32);
      #pragma unroll
      for (int j = 0; j < 4; ++j) {
        acc[0][j] = mfma16(a0, b[j], acc[0][j]);
        acc[1][j] = mfma16(a1, b[j], acc[1][j]);
      }
    }
    chain_epi(acc, bm, wc, lane, out + 2048, c1bf, act);
  }
  __syncthreads();

  // ---- stage 2: c2 = relu(c1 @ W2^T), K=512, A from swizzled LDS ----
  {
    #pragma unroll
    for (int i = 0; i < 2; ++i)
      #pragma unroll
      for (int j = 0; j < 4; ++j) acc[i][j] = (f32x4){0.f, 0.f, 0.f, 0.f};
    const short* B0 = W2b + (size_t)(wc + fr) * 512 + fk;
    #pragma unroll 4
    for (int kt = 0; kt < 16; ++kt) {
      const int r0 = fr, r1 = 16 + fr;
      bf16x8 a0 = *(const bf16x8*)(act + ((r0 * 1024 + kt * 64 + fkg * 16) ^ ((r0 & 7) << 4)));
      bf16x8 a1 = *(const bf16x8*)(act + ((r1 * 1024 + kt * 64 + fkg * 16) ^ ((r1 & 7) << 4)));
      bf16x8 b[4];
      #pragma unroll
      for (int j = 0; j < 4; ++j)
        b[j] = *(const bf16x8*)(B0 + (size_t)j * 16 * 512 + kt * 32);
      #pragma unroll
      for (int j = 0; j < 4; ++j) {
        acc[0][j] = mfma16(a0, b[j], acc[0][j]);
        acc[1][j] = mfma16(a1, b[j], acc[1][j]);
      }
    }
    __syncthreads();   // all waves done READING c1 before overwrite
    chain_epi(acc, bm, wc, lane, out + 2560, c2bf, act);
  }
  __syncthreads();

  // ---- stage 3: c3 = relu(c2 @ W3^T), K=512, A from swizzled LDS ----
  {
    #pragma unroll
    for (int i = 0; i < 2; ++i)
      #pragma unroll
      for (int j = 0; j < 4; ++j) acc[i][j] = (f32x4){0.f, 0.f, 0.f, 0.f};
    const short* B0 = W3b + (size_t)(wc + fr) * 512 + fk;
    #pragma unroll 4
    for (int kt = 0; kt < 16; ++kt) {
      const int r0 = fr, r1 = 16 + fr;
      bf16x8 a0 = *(const bf16x8*)(act + ((r0 * 1024 + kt * 64 + fkg * 16) ^ ((r0 & 7) << 4)));
      bf16x8 a1 = *(const bf16x8*)(act + ((r1 * 1024 + kt * 64 + fkg * 16) ^ ((r1 & 7) << 4)));
      bf16x8 b[4];
      #pragma unroll
      for (int j = 0; j < 4; ++j)
        b[j] = *(const bf16x8*)(B0 + (size_t)j * 16 * 512 + kt * 32);
      #pragma unroll
      for (int j = 0; j < 4; ++j) {
        acc[0][j] = mfma16(a0, b[j], acc[0][j]);
        acc[1][j] = mfma16(a1, b[j], acc[1][j]);
      }
    }
    chain_epi(acc, bm, wc, lane, out + 3072, c3bf, nullptr);
  }
}

// ---------------------------------------------------------------------------
// eta kernel: 1024 blocks (4/CU), 256 thr, barrier-free fragment-from-global.
// block tile 64x128; waves 2x2 -> wave tile 32x64 (MR=2, NR=4).
// cols [0,1024)=eta1, [1024,1536)=eta2, [1536,2048)=eta3.
// ---------------------------------------------------------------------------
__global__ __launch_bounds__(256)
void eta_kernel(const short* __restrict__ c1bf, const short* __restrict__ c2bf,
                const short* __restrict__ c3bf,
                const short* __restrict__ W1T, const short* __restrict__ W2T,
                const short* __restrict__ W3T,
                const float* __restrict__ b1, const float* __restrict__ b2,
                const float* __restrict__ b3, float* __restrict__ out)
{
  const int blk  = blockIdx.x;
  const int brow = blk & 63;
  const int bcol = blk >> 6;            // 0..15
  const short* A; const short* Bw; const float* bias; int outoff, bn;
  if (bcol < 8)       { A = c1bf; Bw = W1T; bias = b1; outoff = 0;    bn = bcol * 128; }
  else if (bcol < 12) { A = c2bf; Bw = W2T; bias = b2; outoff = 1024; bn = (bcol - 8) * 128; }
  else                { A = c3bf; Bw = W3T; bias = b3; outoff = 1536; bn = (bcol - 12) * 128; }
  const int bm   = brow * 64;
  const int tid  = threadIdx.x;
  const int lane = tid & 63;
  const int wid  = tid >> 6;
  const int wr   = (wid >> 1) * 32;
  const int wc   = (wid & 1) * 64;
  const int fr   = lane & 15;
  const int fk   = (lane >> 4) * 8;

  f32x4 acc[2][4] = {};
  const short* A0 = A  + (size_t)(bm + wr + fr) * 512 + fk;
  const short* B0 = Bw + (size_t)(bn + wc + fr) * 512 + fk;
  #pragma unroll 4
  for (int kt = 0; kt < 16; ++kt) {
    bf16x8 a0 = *(const bf16x8*)(A0 + kt * 32);
    bf16x8 a1 = *(const bf16x8*)(A0 + 16 * 512 + kt * 32);
    bf16x8 b[4];
    #pragma unroll
    for (int j = 0; j < 4; ++j)
      b[j] = *(const bf16x8*)(B0 + (size_t)j * 16 * 512 + kt * 32);
    #pragma unroll
    for (int j = 0; j < 4; ++j) {
      acc[0][j] = mfma16(a0, b[j], acc[0][j]);
      acc[1][j] = mfma16(a1, b[j], acc[1][j]);
    }
  }
  const int q0 = (lane >> 4) * 4;
  #pragma unroll
  for (int i = 0; i < 2; ++i) {
    #pragma unroll
    for (int j = 0; j < 4; ++j) {
      const int col = bn + wc + j * 16 + fr;
      const float bv = bias[col];
      #pragma unroll
      for (int q = 0; q < 4; ++q) {
        const int row = bm + wr + i * 16 + q0 + q;
        out[(size_t)row * OUT_LD + outoff + col] = acc[i][j][q] + bv;
      }
    }
  }
}

// ---------------------------------------------------------------------------
// fused prep: blocks [0,5120) straight f32->bf16 conversions (float4 jobs),
// blocks [5120,6144) LDS-tiled transposes W1T/W2T/W3T.
// ---------------------------------------------------------------------------
__global__ void prep(const float* __restrict__ Y, const float* __restrict__ W1,
                     const float* __restrict__ W2, const float* __restrict__ W3,
                     short* __restrict__ Ybf, short* __restrict__ W1b,
                     short* __restrict__ W2b, short* __restrict__ W3b,
                     short* __restrict__ W1T, short* __restrict__ W2T,
                     short* __restrict__ W3T)
{
  __shared__ short s[32][33];
  const int b = blockIdx.x;
  if (b < 5120) {
    const int i = b * 256 + threadIdx.x;   // 1310720 float4 jobs total
    const float* src; short* dst; int off;
    if (i < 1048576)      { src = Y;  dst = Ybf; off = i; }
    else if (i < 1179648) { src = W1; dst = W1b; off = i - 1048576; }
    else if (i < 1245184) { src = W2; dst = W2b; off = i - 1179648; }
    else                  { src = W3; dst = W3b; off = i - 1245184; }
    const float4 v = reinterpret_cast<const float4*>(src)[off];
    short4 o;
    o.x = f2bf(v.x); o.y = f2bf(v.y); o.z = f2bf(v.z); o.w = f2bf(v.w);
    reinterpret_cast<short4*>(dst)[off] = o;
  } else {
    const int t = b - 5120;
    const float* in; short* outp; int R, C, ti, tj;
    if (t < 512)      { in = W1; outp = W1T; R = 512; C = 1024; ti = t >> 5; tj = t & 31; }
    else if (t < 768) { int l = t - 512; in = W2; outp = W2T; R = 512; C = 512; ti = l >> 4; tj = l & 15; }
    else              { int l = t - 768; in = W3; outp = W3T; R = 512; C = 512; ti = l >> 4; tj = l & 15; }
    const int r0 = ti * 32, c0 = tj * 32;
    const int tx = threadIdx.x & 31, ty = threadIdx.x >> 5;
    #pragma unroll
    for (int q = 0; q < 4; ++q)
      s[ty + q * 8][tx] = f2bf(in[(size_t)(r0 + ty + q * 8) * C + c0 + tx]);
    __syncthreads();
    #pragma unroll
    for (int q = 0; q < 4; ++q)
      outp[(size_t)(c0 + ty + q * 8) * R + r0 + tx] = s[tx][ty + q * 8];
  }
}

extern "C" void kernel_launch(void* const* d_in, const int* in_sizes, int n_in,
                              void* d_out, int out_size, void* d_ws, size_t ws_size,
                              hipStream_t stream) {
  const float* Y  = (const float*)d_in[0];
  const float* W1 = (const float*)d_in[1];
  const float* W2 = (const float*)d_in[2];
  const float* W3 = (const float*)d_in[3];
  const float* b1 = (const float*)d_in[4];
  const float* b2 = (const float*)d_in[5];
  const float* b3 = (const float*)d_in[6];
  float* out = (float*)d_out;

  if (ws_size < 25165824) return;  // need 24 MB scratch

  char* ws = (char*)d_ws;
  short* Ybf  = (short*)(ws);                  // [4096][1024]
  short* c1bf = (short*)(ws + 8388608);        // [4096][512]
  short* c2bf = (short*)(ws + 12582912);       // [4096][512]
  short* c3bf = (short*)(ws + 16777216);       // [4096][512]
  short* W1b  = (short*)(ws + 20971520);       // [512][1024]
  short* W2b  = (short*)(ws + 22020096);       // [512][512]
  short* W3b  = (short*)(ws + 22544384);       // [512][512]
  short* W1T  = (short*)(ws + 23068672);       // [1024][512]
  short* W2T  = (short*)(ws + 24117248);       // [512][512]
  short* W3T  = (short*)(ws + 24641536);       // [512][512]

  prep<<<6144, 256, 0, stream>>>(Y, W1, W2, W3, Ybf, W1b, W2b, W3b, W1T, W2T, W3T);
  chain_kernel<<<128, 512, 0, stream>>>(Ybf, W1b, W2b, W3b, c1bf, c2bf, c3bf, out);
  eta_kernel<<<1024, 256, 0, stream>>>(c1bf, c2bf, c3bf, W1T, W2T, W3T, b1, b2, b3, out);
}

// Round 5
// 135.904 us; speedup vs baseline: 1.5760x; 1.5760x over previous
//
#include <hip/hip_runtime.h>
#include <hip/hip_bf16.h>
#include <cstdint>

#define OUT_LD 3584

typedef __bf16 bf16x8 __attribute__((ext_vector_type(8)));
typedef float  f32x4  __attribute__((ext_vector_type(4)));

__device__ __forceinline__ short f2bf(float v) {
  __hip_bfloat16 h = __float2bfloat16(v);
  return *reinterpret_cast<short*>(&h);
}

__device__ __forceinline__ void async16(const short* g, short* l) {
  __builtin_amdgcn_global_load_lds(
      (const __attribute__((address_space(1))) unsigned int*)g,
      (__attribute__((address_space(3))) unsigned int*)l, 16, 0, 0);
}

// ---------------------------------------------------------------------------
// 64x64-tile, 256-thr (4 waves 2x2), double-buffered minimum-2-phase GEMM.
// A:[M,K] B:[N,K] bf16 row-major (ld=K). C = A @ B^T tile at (bm,bn).
// LDS tiles are XOR-swizzled (T2, rule 21 both-sides): element (row, kgroup g)
// lives at LDS group g^(row&7); staged via pre-swizzled GLOBAL source column
// with a linear global_load_lds dest; ds_read applies the same XOR.
// RELU=true : rv=relu(acc); fout[(bm+row)*OUT_LD + bn+col]=rv (f32, z-block);
//             cbf[(bm+row)*512 + bn+col]=bf16(rv)
// RELU=false: fout[(bm+row)*OUT_LD + outoff + bn+col]=acc + bias[bn+col]
// ---------------------------------------------------------------------------
template<bool RELU>
__device__ __forceinline__ void gemm64(
    const short* __restrict__ A, const short* __restrict__ B, int K,
    int bm, int bn, const float* __restrict__ bias, int outoff,
    float* __restrict__ fout, short* __restrict__ cbf)
{
  __shared__ __align__(16) short sA[2][64 * 64];
  __shared__ __align__(16) short sB[2][64 * 64];

  const int tid  = threadIdx.x;
  const int lane = tid & 63;
  const int wid  = tid >> 6;
  const int wr   = (wid >> 1) * 32;
  const int wc   = (wid & 1) * 32;
  const int fr   = lane & 15;
  const int fkg  = lane >> 4;           // k-group 0..3 within 32-k half

  // staging map: thread t, pass p(0..1): tile row = p*32 + (t>>3);
  // global k-group = (t&7) ^ (row&7)  [pre-swizzle so LDS stays linear-dest]
  const int srow = tid >> 3;
  const int sg   = (tid & 7) ^ (srow & 7);
  const short* ga0 = A + (size_t)(bm + srow) * K + sg * 8;
  const short* gb0 = B + (size_t)(bn + srow) * K + sg * 8;

  f32x4 acc[2][2] = {};
  const int nk = K >> 6;

  auto stage = [&](int buf, int kt) {
    const int koff = kt * 64;
    #pragma unroll
    for (int p = 0; p < 2; ++p) {
      async16(ga0 + (size_t)(p * 32) * K + koff, &sA[buf][p * 2048 + tid * 8]);
      async16(gb0 + (size_t)(p * 32) * K + koff, &sB[buf][p * 2048 + tid * 8]);
    }
  };

  stage(0, 0);
  __syncthreads();                 // prologue drain
  int cur = 0;
  for (int kt = 0; kt < nk; ++kt) {
    if (kt + 1 < nk) stage(cur ^ 1, kt + 1);   // issue next tile BEFORE compute
    #pragma unroll
    for (int kk = 0; kk < 2; ++kk) {
      bf16x8 a[2], b[2];
      #pragma unroll
      for (int i = 0; i < 2; ++i) {
        const int row = wr + i * 16 + fr;
        a[i] = *(const bf16x8*)((const char*)&sA[cur][0] +
                 row * 128 + (((kk * 4 + fkg) ^ (row & 7)) * 16));
      }
      #pragma unroll
      for (int j = 0; j < 2; ++j) {
        const int row = wc + j * 16 + fr;
        b[j] = *(const bf16x8*)((const char*)&sB[cur][0] +
                 row * 128 + (((kk * 4 + fkg) ^ (row & 7)) * 16));
      }
      #pragma unroll
      for (int i = 0; i < 2; ++i)
        #pragma unroll
        for (int j = 0; j < 2; ++j)
          acc[i][j] = __builtin_amdgcn_mfma_f32_16x16x32_bf16(a[i], b[j], acc[i][j], 0, 0, 0);
    }
    __syncthreads();   // vmcnt(0): next buffer staged; all reads of cur done
    cur ^= 1;
  }

  // epilogue: C/D map col=lane&15, row=(lane>>4)*4+q
  const int q0 = (lane >> 4) * 4;
  #pragma unroll
  for (int i = 0; i < 2; ++i) {
    #pragma unroll
    for (int j = 0; j < 2; ++j) {
      const int col = bn + wc + j * 16 + fr;
      #pragma unroll
      for (int q = 0; q < 4; ++q) {
        const int row = bm + wr + i * 16 + q0 + q;
        float v = acc[i][j][q];
        if (RELU) {
          float rv = v > 0.f ? v : 0.f;
          fout[(size_t)row * OUT_LD + col] = rv;
          cbf[(size_t)row * 512 + col] = f2bf(rv);
        } else {
          fout[(size_t)row * OUT_LD + outoff + col] = v + bias[col];
        }
      }
    }
  }
}

// chain GEMM: grid (M/64, N/64); writes z-block (f32) + bf16 activation
__global__ __launch_bounds__(256)
void gemm_relu(const short* __restrict__ A, const short* __restrict__ B, int K,
               float* __restrict__ zout, short* __restrict__ cbf) {
  gemm64<true>(A, B, K, blockIdx.x * 64, blockIdx.y * 64, nullptr, 0, zout, cbf);
}

// grouped eta GEMM: grid (64, 32); y<16 eta1, y<24 eta2, else eta3
__global__ __launch_bounds__(256)
void gemm_eta(const short* __restrict__ c1, const short* __restrict__ c2,
              const short* __restrict__ c3, const short* __restrict__ W1T,
              const short* __restrict__ W2T, const short* __restrict__ W3T,
              const float* __restrict__ b1, const float* __restrict__ b2,
              const float* __restrict__ b3, float* __restrict__ out) {
  const int y = blockIdx.y;
  const short* A; const short* Bw; const float* bias; int outoff, bn;
  if (y < 16)      { A = c1; Bw = W1T; bias = b1; outoff = 0;    bn = y * 64; }
  else if (y < 24) { A = c2; Bw = W2T; bias = b2; outoff = 1024; bn = (y - 16) * 64; }
  else             { A = c3; Bw = W3T; bias = b3; outoff = 1536; bn = (y - 24) * 64; }
  gemm64<false>(A, Bw, 512, blockIdx.x * 64, bn, bias, outoff, out, nullptr);
}

// ---------------------------------------------------------------------------
// fused prep: blocks [0,5120) straight f32->bf16 conversions (float4 jobs),
// blocks [5120,6144) LDS-tiled transposes W1T/W2T/W3T.
// ---------------------------------------------------------------------------
__global__ void prep(const float* __restrict__ Y, const float* __restrict__ W1,
                     const float* __restrict__ W2, const float* __restrict__ W3,
                     short* __restrict__ Ybf, short* __restrict__ W1b,
                     short* __restrict__ W2b, short* __restrict__ W3b,
                     short* __restrict__ W1T, short* __restrict__ W2T,
                     short* __restrict__ W3T)
{
  __shared__ short s[32][33];
  const int b = blockIdx.x;
  if (b < 5120) {
    const int i = b * 256 + threadIdx.x;   // 1310720 float4 jobs total
    const float* src; short* dst; int off;
    if (i < 1048576)      { src = Y;  dst = Ybf; off = i; }
    else if (i < 1179648) { src = W1; dst = W1b; off = i - 1048576; }
    else if (i < 1245184) { src = W2; dst = W2b; off = i - 1179648; }
    else                  { src = W3; dst = W3b; off = i - 1245184; }
    const float4 v = reinterpret_cast<const float4*>(src)[off];
    short4 o;
    o.x = f2bf(v.x); o.y = f2bf(v.y); o.z = f2bf(v.z); o.w = f2bf(v.w);
    reinterpret_cast<short4*>(dst)[off] = o;
  } else {
    const int t = b - 5120;
    const float* in; short* outp; int R, C, ti, tj;
    if (t < 512)      { in = W1; outp = W1T; R = 512; C = 1024; ti = t >> 5; tj = t & 31; }
    else if (t < 768) { int l = t - 512; in = W2; outp = W2T; R = 512; C = 512; ti = l >> 4; tj = l & 15; }
    else              { int l = t - 768; in = W3; outp = W3T; R = 512; C = 512; ti = l >> 4; tj = l & 15; }
    const int r0 = ti * 32, c0 = tj * 32;
    const int tx = threadIdx.x & 31, ty = threadIdx.x >> 5;
    #pragma unroll
    for (int q = 0; q < 4; ++q)
      s[ty + q * 8][tx] = f2bf(in[(size_t)(r0 + ty + q * 8) * C + c0 + tx]);
    __syncthreads();
    #pragma unroll
    for (int q = 0; q < 4; ++q)
      outp[(size_t)(c0 + ty + q * 8) * R + r0 + tx] = s[tx][ty + q * 8];
  }
}

extern "C" void kernel_launch(void* const* d_in, const int* in_sizes, int n_in,
                              void* d_out, int out_size, void* d_ws, size_t ws_size,
                              hipStream_t stream) {
  const float* Y  = (const float*)d_in[0];
  const float* W1 = (const float*)d_in[1];
  const float* W2 = (const float*)d_in[2];
  const float* W3 = (const float*)d_in[3];
  const float* b1 = (const float*)d_in[4];
  const float* b2 = (const float*)d_in[5];
  const float* b3 = (const float*)d_in[6];
  float* out = (float*)d_out;

  if (ws_size < 25165824) return;  // need 24 MB scratch

  char* ws = (char*)d_ws;
  short* Ybf  = (short*)(ws);                  // [4096][1024]
  short* c1bf = (short*)(ws + 8388608);        // [4096][512]
  short* c2bf = (short*)(ws + 12582912);       // [4096][512]
  short* c3bf = (short*)(ws + 16777216);       // [4096][512]
  short* W1b  = (short*)(ws + 20971520);       // [512][1024]
  short* W2b  = (short*)(ws + 22020096);       // [512][512]
  short* W3b  = (short*)(ws + 22544384);       // [512][512]
  short* W1T  = (short*)(ws + 23068672);       // [1024][512]
  short* W2T  = (short*)(ws + 24117248);       // [512][512]
  short* W3T  = (short*)(ws + 24641536);       // [512][512]

  prep<<<6144, 256, 0, stream>>>(Y, W1, W2, W3, Ybf, W1b, W2b, W3b, W1T, W2T, W3T);

  // c1 = relu(Y @ W1^T); z1 -> out[:,2048:2560)
  gemm_relu<<<dim3(64, 8), 256, 0, stream>>>(Ybf, W1b, 1024, out + 2048, c1bf);
  // c2 = relu(c1 @ W2^T); z2 -> out[:,2560:3072)
  gemm_relu<<<dim3(64, 8), 256, 0, stream>>>(c1bf, W2b, 512, out + 2560, c2bf);
  // c3 = relu(c2 @ W3^T); z3 -> out[:,3072:3584)
  gemm_relu<<<dim3(64, 8), 256, 0, stream>>>(c2bf, W3b, 512, out + 3072, c3bf);
  // eta1|eta2|eta3 -> out[:,0:2048)
  gemm_eta<<<dim3(64, 32), 256, 0, stream>>>(c1bf, c2bf, c3bf, W1T, W2T, W3T, b1, b2, b3, out);
}

// Round 6
// 127.132 us; speedup vs baseline: 1.6847x; 1.0690x over previous
//
#include <hip/hip_runtime.h>
#include <hip/hip_bf16.h>
#include <cstdint>

#define OUT_LD 3584

typedef __bf16 bf16x8 __attribute__((ext_vector_type(8)));
typedef float  f32x4  __attribute__((ext_vector_type(4)));

__device__ __forceinline__ short f2bf(float v) {
  __hip_bfloat16 h = __float2bfloat16(v);
  return *reinterpret_cast<short*>(&h);
}

__device__ __forceinline__ void async16(const short* g, short* l) {
  __builtin_amdgcn_global_load_lds(
      (const __attribute__((address_space(1))) unsigned int*)g,
      (__attribute__((address_space(3))) unsigned int*)l, 16, 0, 0);
}

struct __align__(16) SBuf {
  short sA[3][64 * 64];
  short sB[3][64 * 64];
};

// ---------------------------------------------------------------------------
// 64x64-tile, 256-thr (4 waves 2x2) GEMM, 3-buffer pipeline with COUNTED
// vmcnt (T3+T4): tile kt+2 is staged right after the post-compute barrier and
// its loads stay in flight across barriers; steady-state wait is vmcnt(4),
// never 0. LDS XOR-swizzled both-sides (T2, rule 21): global k-group
// (t&7)^(row&7) -> linear LDS dest; ds_read applies the same XOR.
// A:[M,K] B:[N,K] bf16 row-major. C = A @ B^T tile at (bm,bn).
// RELU=true : rv=relu(acc); fout[(row)*OUT_LD+col]=rv; cbf[row*512+col]=bf16(rv)
// RELU=false: fout[row*OUT_LD + outoff + col] = acc + bias[col]
// ---------------------------------------------------------------------------
template<bool RELU>
__device__ __forceinline__ void gemm64(
    SBuf& s, const short* __restrict__ A, const short* __restrict__ B, int K,
    int bm, int bn, const float* __restrict__ bias, int outoff,
    float* __restrict__ fout, short* __restrict__ cbf)
{
  const int tid  = threadIdx.x;
  const int lane = tid & 63;
  const int wid  = tid >> 6;
  const int wr   = (wid >> 1) * 32;
  const int wc   = (wid & 1) * 32;
  const int fr   = lane & 15;
  const int fkg  = lane >> 4;

  const int srow = tid >> 3;
  const int sg   = (tid & 7) ^ (srow & 7);
  const short* ga0 = A + (size_t)(bm + srow) * K + sg * 8;
  const short* gb0 = B + (size_t)(bn + srow) * K + sg * 8;

  f32x4 acc[2][2] = {};
  const int nk = K >> 6;

  auto stage = [&](int buf, int kt) {
    const int koff = kt * 64;
    async16(ga0 + koff,                 &s.sA[buf][tid * 8]);
    async16(ga0 + 32 * (size_t)K + koff, &s.sA[buf][2048 + tid * 8]);
    async16(gb0 + koff,                 &s.sB[buf][tid * 8]);
    async16(gb0 + 32 * (size_t)K + koff, &s.sB[buf][2048 + tid * 8]);
  };

  stage(0, 0);
  stage(1, 1);                       // 8 loads/thread in flight
  for (int kt = 0; kt < nk; ++kt) {
    const int cur = kt % 3;
    if (kt < nk - 1) asm volatile("s_waitcnt vmcnt(4)" ::: "memory");  // tile kt landed
    else             asm volatile("s_waitcnt vmcnt(0)" ::: "memory");  // last tile
    __builtin_amdgcn_s_barrier();
    __builtin_amdgcn_s_setprio(1);
    #pragma unroll
    for (int kk = 0; kk < 2; ++kk) {
      bf16x8 a[2], b[2];
      #pragma unroll
      for (int i = 0; i < 2; ++i) {
        const int row = wr + i * 16 + fr;
        a[i] = *(const bf16x8*)((const char*)&s.sA[cur][0] +
                 row * 128 + (((kk * 4 + fkg) ^ (row & 7)) * 16));
      }
      #pragma unroll
      for (int j = 0; j < 2; ++j) {
        const int row = wc + j * 16 + fr;
        b[j] = *(const bf16x8*)((const char*)&s.sB[cur][0] +
                 row * 128 + (((kk * 4 + fkg) ^ (row & 7)) * 16));
      }
      #pragma unroll
      for (int i = 0; i < 2; ++i)
        #pragma unroll
        for (int j = 0; j < 2; ++j)
          acc[i][j] = __builtin_amdgcn_mfma_f32_16x16x32_bf16(a[i], b[j], acc[i][j], 0, 0, 0);
    }
    __builtin_amdgcn_s_setprio(0);
    if (kt + 2 < nk) {
      __builtin_amdgcn_s_barrier();  // all waves done reading buf (kt-1)%3
      stage((kt + 2) % 3, kt + 2);   // refill it; stays in flight 2 phases
    }
  }

  // epilogue: C/D map col=lane&15, row=(lane>>4)*4+q
  const int q0 = (lane >> 4) * 4;
  #pragma unroll
  for (int i = 0; i < 2; ++i) {
    #pragma unroll
    for (int j = 0; j < 2; ++j) {
      const int col = bn + wc + j * 16 + fr;
      #pragma unroll
      for (int q = 0; q < 4; ++q) {
        const int row = bm + wr + i * 16 + q0 + q;
        float v = acc[i][j][q];
        if (RELU) {
          float rv = v > 0.f ? v : 0.f;
          fout[(size_t)row * OUT_LD + col] = rv;
          cbf[(size_t)row * 512 + col] = f2bf(rv);
        } else {
          fout[(size_t)row * OUT_LD + outoff + col] = v + bias[col];
        }
      }
    }
  }
}

// P1: c1 = relu(Y @ W1b^T), 512 blocks (64 rows x 8 cols), XCD-chunked
__global__ __launch_bounds__(256)
void k_p1(const short* __restrict__ Ybf, const short* __restrict__ W1b,
          float* __restrict__ out, short* __restrict__ c1bf) {
  __shared__ SBuf s;
  const int b = blockIdx.x;
  const int swz = (b & 7) * 64 + (b >> 3);          // cpx = 512/8
  gemm64<true>(s, Ybf, W1b, 1024, (swz >> 3) * 64, (swz & 7) * 64,
               nullptr, 0, out + 2048, c1bf);
}

// P2: {c2 (512 tiles)} ∪ {eta1 (1024 tiles)} — both depend only on c1
__global__ __launch_bounds__(256)
void k_p2(const short* __restrict__ c1bf, const short* __restrict__ W2b,
          const short* __restrict__ W1T, const float* __restrict__ b1,
          float* __restrict__ out, short* __restrict__ c2bf) {
  __shared__ SBuf s;
  const int b = blockIdx.x;
  const int swz = (b & 7) * 192 + (b >> 3);         // cpx = 1536/8
  if (swz < 512) {
    gemm64<true>(s, c1bf, W2b, 512, (swz >> 3) * 64, (swz & 7) * 64,
                 nullptr, 0, out + 2560, c2bf);
  } else {
    const int t = swz - 512;                        // 64 rows x 16 cols
    gemm64<false>(s, c1bf, W1T, 512, (t >> 4) * 64, (t & 15) * 64,
                  b1, 0, out, nullptr);
  }
}

// P3: {c3 (512 tiles)} ∪ {eta2 (512 tiles)} — both depend only on c2
__global__ __launch_bounds__(256)
void k_p3(const short* __restrict__ c2bf, const short* __restrict__ W3b,
          const short* __restrict__ W2T, const float* __restrict__ b2,
          float* __restrict__ out, short* __restrict__ c3bf) {
  __shared__ SBuf s;
  const int b = blockIdx.x;
  const int swz = (b & 7) * 128 + (b >> 3);         // cpx = 1024/8
  if (swz < 512) {
    gemm64<true>(s, c2bf, W3b, 512, (swz >> 3) * 64, (swz & 7) * 64,
                 nullptr, 0, out + 3072, c3bf);
  } else {
    const int t = swz - 512;                        // 64 rows x 8 cols
    gemm64<false>(s, c2bf, W2T, 512, (t >> 3) * 64, (t & 7) * 64,
                  b2, 1024, out, nullptr);
  }
}

// P4: eta3 (512 tiles) — depends on c3
__global__ __launch_bounds__(256)
void k_p4(const short* __restrict__ c3bf, const short* __restrict__ W3T,
          const float* __restrict__ b3, float* __restrict__ out) {
  __shared__ SBuf s;
  const int b = blockIdx.x;
  const int swz = (b & 7) * 64 + (b >> 3);
  gemm64<false>(s, c3bf, W3T, 512, (swz >> 3) * 64, (swz & 7) * 64,
                b3, 1536, out, nullptr);
}

// ---------------------------------------------------------------------------
// fused prep: blocks [0,5120) straight f32->bf16 conversions (float4 jobs),
// blocks [5120,6144) LDS-tiled transposes W1T/W2T/W3T.
// ---------------------------------------------------------------------------
__global__ void prep(const float* __restrict__ Y, const float* __restrict__ W1,
                     const float* __restrict__ W2, const float* __restrict__ W3,
                     short* __restrict__ Ybf, short* __restrict__ W1b,
                     short* __restrict__ W2b, short* __restrict__ W3b,
                     short* __restrict__ W1T, short* __restrict__ W2T,
                     short* __restrict__ W3T)
{
  __shared__ short s[32][33];
  const int b = blockIdx.x;
  if (b < 5120) {
    const int i = b * 256 + threadIdx.x;   // 1310720 float4 jobs total
    const float* src; short* dst; int off;
    if (i < 1048576)      { src = Y;  dst = Ybf; off = i; }
    else if (i < 1179648) { src = W1; dst = W1b; off = i - 1048576; }
    else if (i < 1245184) { src = W2; dst = W2b; off = i - 1179648; }
    else                  { src = W3; dst = W3b; off = i - 1245184; }
    const float4 v = reinterpret_cast<const float4*>(src)[off];
    short4 o;
    o.x = f2bf(v.x); o.y = f2bf(v.y); o.z = f2bf(v.z); o.w = f2bf(v.w);
    reinterpret_cast<short4*>(dst)[off] = o;
  } else {
    const int t = b - 5120;
    const float* in; short* outp; int R, C, ti, tj;
    if (t < 512)      { in = W1; outp = W1T; R = 512; C = 1024; ti = t >> 5; tj = t & 31; }
    else if (t < 768) { int l = t - 512; in = W2; outp = W2T; R = 512; C = 512; ti = l >> 4; tj = l & 15; }
    else              { int l = t - 768; in = W3; outp = W3T; R = 512; C = 512; ti = l >> 4; tj = l & 15; }
    const int r0 = ti * 32, c0 = tj * 32;
    const int tx = threadIdx.x & 31, ty = threadIdx.x >> 5;
    #pragma unroll
    for (int q = 0; q < 4; ++q)
      s[ty + q * 8][tx] = f2bf(in[(size_t)(r0 + ty + q * 8) * C + c0 + tx]);
    __syncthreads();
    #pragma unroll
    for (int q = 0; q < 4; ++q)
      outp[(size_t)(c0 + ty + q * 8) * R + r0 + tx] = s[tx][ty + q * 8];
  }
}

extern "C" void kernel_launch(void* const* d_in, const int* in_sizes, int n_in,
                              void* d_out, int out_size, void* d_ws, size_t ws_size,
                              hipStream_t stream) {
  const float* Y  = (const float*)d_in[0];
  const float* W1 = (const float*)d_in[1];
  const float* W2 = (const float*)d_in[2];
  const float* W3 = (const float*)d_in[3];
  const float* b1 = (const float*)d_in[4];
  const float* b2 = (const float*)d_in[5];
  const float* b3 = (const float*)d_in[6];
  float* out = (float*)d_out;

  if (ws_size < 25165824) return;  // need 24 MB scratch

  char* ws = (char*)d_ws;
  short* Ybf  = (short*)(ws);                  // [4096][1024]
  short* c1bf = (short*)(ws + 8388608);        // [4096][512]
  short* c2bf = (short*)(ws + 12582912);       // [4096][512]
  short* c3bf = (short*)(ws + 16777216);       // [4096][512]
  short* W1b  = (short*)(ws + 20971520);       // [512][1024]
  short* W2b  = (short*)(ws + 22020096);       // [512][512]
  short* W3b  = (short*)(ws + 22544384);       // [512][512]
  short* W1T  = (short*)(ws + 23068672);       // [1024][512]
  short* W2T  = (short*)(ws + 24117248);       // [512][512]
  short* W3T  = (short*)(ws + 24641536);       // [512][512]

  prep<<<6144, 256, 0, stream>>>(Y, W1, W2, W3, Ybf, W1b, W2b, W3b, W1T, W2T, W3T);
  k_p1<<<512, 256, 0, stream>>>(Ybf, W1b, out, c1bf);
  k_p2<<<1536, 256, 0, stream>>>(c1bf, W2b, W1T, b1, out, c2bf);
  k_p3<<<1024, 256, 0, stream>>>(c2bf, W3b, W2T, b2, out, c3bf);
  k_p4<<<512, 256, 0, stream>>>(c3bf, W3T, b3, out);
}